// Round 11
// baseline (599.671 us; speedup 1.0000x reference)
//
#include <hip/hip_runtime.h>

#define B_    512
#define KD    20000
#define EMBD  256
#define HIDD  512
#define NEMB  200000
#define SPLITS 25
#define KSPAN  800   // 20000 / 25, = 25 k-steps of 32
#define TILE_N 128   // k4 n-panel per block -> 512B per out row per block

typedef __attribute__((ext_vector_type(8))) short bf16x8;
typedef __attribute__((ext_vector_type(4))) float f32x4;
typedef __attribute__((ext_vector_type(8))) unsigned short u16x8;

__device__ __forceinline__ unsigned short f2bf(float f) {
  unsigned int u = __float_as_uint(f);
  return (unsigned short)((u + 0x7fffu + ((u >> 16) & 1u)) >> 16);  // RNE
}

__device__ __forceinline__ float selu_f(float x) {
  const float kScale = 1.0507009873554805f;
  const float kSA    = 1.7580993408473766f;  // scale*alpha
  return x > 0.0f ? kScale * x : kSA * (__expf(x) - 1.0f);
}

// raw barrier: LDS-visibility only (lgkmcnt), does NOT drain vmcnt ->
// global (nt) stores stay in flight across substeps.
__device__ __forceinline__ void barrier_lgkm() {
  asm volatile("s_waitcnt lgkmcnt(0)" ::: "memory");
  __builtin_amdgcn_s_barrier();
  __builtin_amdgcn_sched_barrier(0);
}

// pack 8 f32 -> bf16x8 via HW packed cvt (RNE), 4 inst
__device__ __forceinline__ bf16x8 cvt8(f32x4 x, f32x4 y) {
  union { unsigned int w[4]; bf16x8 v; } u;
  asm("v_cvt_pk_bf16_f32 %0, %1, %2" : "=v"(u.w[0]) : "v"(x[0]), "v"(x[1]));
  asm("v_cvt_pk_bf16_f32 %0, %1, %2" : "=v"(u.w[1]) : "v"(x[2]), "v"(x[3]));
  asm("v_cvt_pk_bf16_f32 %0, %1, %2" : "=v"(u.w[2]) : "v"(y[0]), "v"(y[1]));
  asm("v_cvt_pk_bf16_f32 %0, %1, %2" : "=v"(u.w[3]) : "v"(y[2]), "v"(y[3]));
  return u.v;
}

// load 8 consecutive f32 and pack to bf16x8 (16B-aligned source)
__device__ __forceinline__ bf16x8 load8f(const float* __restrict__ p) {
  float4 a = *(const float4*)p;
  float4 b = *(const float4*)(p + 4);
  bf16x8 r;
  r[0] = (short)f2bf(a.x); r[1] = (short)f2bf(a.y);
  r[2] = (short)f2bf(a.z); r[3] = (short)f2bf(a.w);
  r[4] = (short)f2bf(b.x); r[5] = (short)f2bf(b.y);
  r[6] = (short)f2bf(b.z); r[7] = (short)f2bf(b.w);
  return r;
}

// ---------------- K0: gather+pack en_emb[act] -> wactP[k/8][e=256][8] bf16 --
__global__ void k0_pack(const int* __restrict__ act,
                        const float* __restrict__ en_emb,
                        unsigned short* __restrict__ wactP) {
  const int tid = threadIdx.x;       // = e (0..255)
  const int k0 = blockIdx.x * 8;
  const int is64 = ((act[1] | act[3] | act[5] | act[7]) == 0) ? 1 : 0;
  int idx[8];
#pragma unroll
  for (int j = 0; j < 8; ++j)
    idx[j] = is64 ? act[(size_t)(k0 + j) * 2] : act[k0 + j];
  u16x8 v;
#pragma unroll
  for (int j = 0; j < 8; ++j)
    v[j] = f2bf(en_emb[(size_t)idx[j] * EMBD + tid]);
  *(u16x8*)(wactP + (size_t)k0 * EMBD + tid * 8) = v;
}

// ---------------- K1 (packed): split-K dense GEMM: part[kz] += rin @ wactP --
// grid (4,2,25), 512 thr (8 waves 4Mx2N), block tile 128m x 128n:
// rin read exactly ONCE from HBM (was 4x), wactP duplication 8x -> 4x.
__global__ __launch_bounds__(512)
void k1_dense(const float* __restrict__ rin,
              const unsigned short* __restrict__ wactP,
              float* __restrict__ part) {
  const int tid = threadIdx.x;
  const int lane = tid & 63, wave = tid >> 6;
  const int wM = wave >> 1, wN = wave & 1;   // 4(M) x 2(N)
  const int g = lane >> 4, r16 = lane & 15;
  const int m0 = blockIdx.x * 128 + wM * 32;
  const int n0 = blockIdx.y * 128 + wN * 64;
  const int kz = blockIdx.z;

  const f32x4 z4 = {0.f, 0.f, 0.f, 0.f};
  f32x4 acc[2][4];  // [fm][fn]
#pragma unroll
  for (int a = 0; a < 2; ++a)
#pragma unroll
    for (int b = 0; b < 4; ++b) acc[a][b] = z4;

  for (int s = 0; s < 25; ++s) {
    const int kb = kz * KSPAN + s * 32 + g * 8;
    bf16x8 afr[2], bfr[4];
#pragma unroll
    for (int fm = 0; fm < 2; ++fm)
      afr[fm] = load8f(rin + (size_t)(m0 + fm * 16 + r16) * KD + kb);
#pragma unroll
    for (int fn = 0; fn < 4; ++fn) {
      const int e = n0 + fn * 16 + r16;
      bfr[fn] = *(const bf16x8*)(wactP + (size_t)(kb >> 3) * (EMBD * 8) + e * 8);
    }
#pragma unroll
    for (int fm = 0; fm < 2; ++fm)
#pragma unroll
      for (int fn = 0; fn < 4; ++fn)
        acc[fm][fn] = __builtin_amdgcn_mfma_f32_16x16x32_bf16(afr[fm], bfr[fn], acc[fm][fn], 0, 0, 0);
  }
  float* pz = part + (size_t)kz * (B_ * EMBD);
#pragma unroll
  for (int fm = 0; fm < 2; ++fm)
#pragma unroll
    for (int fn = 0; fn < 4; ++fn) {
      const int n = n0 + fn * 16 + r16;
#pragma unroll
      for (int j = 0; j < 4; ++j) {
        const int m = m0 + fm * 16 + g * 4 + j;
        pz[(size_t)m * EMBD + n] = acc[fm][fn][j];
      }
    }
}

// ---------------- K1 (fallback, gather in-loop) -----------------------------
__global__ void k1_gather_gemm(const float* __restrict__ rin,
                               const int* __restrict__ act,
                               const float* __restrict__ en_emb,
                               float* __restrict__ part) {
  const int tid = threadIdx.x;
  const int lane = tid & 63, wave = tid >> 6;
  const int wm = wave >> 1, wn = wave & 1;
  const int g = lane >> 4, r16 = lane & 15;
  const int m0 = blockIdx.x * 64 + wm * 32;
  const int n0 = blockIdx.y * 64 + wn * 32;
  const int kz = blockIdx.z;
  const int is64 = ((act[1] | act[3] | act[5] | act[7]) == 0) ? 1 : 0;

  const f32x4 z4 = {0.f, 0.f, 0.f, 0.f};
  f32x4 acc[2][2];
#pragma unroll
  for (int a = 0; a < 2; ++a)
#pragma unroll
    for (int b = 0; b < 2; ++b) acc[a][b] = z4;

  for (int s = 0; s < 25; ++s) {
    const int k = kz * KSPAN + s * 32;
    const int kb = k + g * 8;
    bf16x8 afr[2];
#pragma unroll
    for (int fm = 0; fm < 2; ++fm)
      afr[fm] = load8f(rin + (size_t)(m0 + fm * 16 + r16) * KD + kb);
    int idx8[8];
#pragma unroll
    for (int j = 0; j < 8; ++j)
      idx8[j] = is64 ? act[(size_t)(kb + j) * 2] : act[kb + j];
    bf16x8 bfr[2];
#pragma unroll
    for (int fn = 0; fn < 2; ++fn) {
      const int e = n0 + fn * 16 + r16;
#pragma unroll
      for (int j = 0; j < 8; ++j)
        bfr[fn][j] = (short)f2bf(en_emb[(size_t)idx8[j] * EMBD + e]);
    }
#pragma unroll
    for (int fm = 0; fm < 2; ++fm)
#pragma unroll
      for (int fn = 0; fn < 2; ++fn)
        acc[fm][fn] = __builtin_amdgcn_mfma_f32_16x16x32_bf16(afr[fm], bfr[fn], acc[fm][fn], 0, 0, 0);
  }
  float* pz = part + (size_t)kz * (B_ * EMBD);
#pragma unroll
  for (int fm = 0; fm < 2; ++fm)
#pragma unroll
    for (int fn = 0; fn < 2; ++fn) {
      const int n = n0 + fn * 16 + r16;
#pragma unroll
      for (int j = 0; j < 4; ++j) {
        const int m = m0 + fm * 16 + g * 4 + j;
        pz[(size_t)m * EMBD + n] = acc[fm][fn][j];
      }
    }
}

// ---------------- K1b: reduce splits + bias + selu -> z1 (f32) --------------
__global__ void k1_reduce(const float* __restrict__ part,
                          const float* __restrict__ en_bias,
                          float* __restrict__ z1) {
  const int i = blockIdx.x * blockDim.x + threadIdx.x;
  float s = 0.f;
#pragma unroll
  for (int p = 0; p < SPLITS; ++p) s += part[(size_t)p * (B_ * EMBD) + i];
  z1[i] = selu_f(s + en_bias[i & (EMBD - 1)]);
}

// ---------------- K2/K3: small MLP GEMM (C = A @ Bw^T), register-only -------
template <int KDIM, int LDA, int LDB, bool BF16OUT>
__global__ void mlp_gemm(const float* __restrict__ A,
                         const float* __restrict__ Bw,
                         const float* __restrict__ bias,
                         float* __restrict__ outF,
                         unsigned short* __restrict__ outB,
                         int ldo) {
  const int tid = threadIdx.x;
  const int lane = tid & 63, wave = tid >> 6;
  const int wm = wave >> 1, wn = wave & 1;
  const int g = lane >> 4, r16 = lane & 15;
  const int m0 = blockIdx.x * 64 + wm * 32;
  const int n0 = blockIdx.y * 64 + wn * 32;

  const f32x4 z4 = {0.f, 0.f, 0.f, 0.f};
  f32x4 acc[2][2];
#pragma unroll
  for (int a = 0; a < 2; ++a)
#pragma unroll
    for (int b = 0; b < 2; ++b) acc[a][b] = z4;

#pragma unroll
  for (int k = 0; k < KDIM; k += 32) {
    const int kb = k + g * 8;
    bf16x8 afr[2], bfr[2];
#pragma unroll
    for (int fm = 0; fm < 2; ++fm)
      afr[fm] = load8f(A + (size_t)(m0 + fm * 16 + r16) * LDA + kb);
#pragma unroll
    for (int fn = 0; fn < 2; ++fn)
      bfr[fn] = load8f(Bw + (size_t)(n0 + fn * 16 + r16) * LDB + kb);
#pragma unroll
    for (int fm = 0; fm < 2; ++fm)
#pragma unroll
      for (int fn = 0; fn < 2; ++fn)
        acc[fm][fn] = __builtin_amdgcn_mfma_f32_16x16x32_bf16(afr[fm], bfr[fn], acc[fm][fn], 0, 0, 0);
  }
#pragma unroll
  for (int fm = 0; fm < 2; ++fm)
#pragma unroll
    for (int fn = 0; fn < 2; ++fn) {
      const int n = n0 + fn * 16 + r16;
      const float bv = bias[n];
#pragma unroll
      for (int j = 0; j < 4; ++j) {
        const int m = m0 + fm * 16 + g * 4 + j;
        const float v = selu_f(acc[fm][fn][j] + bv);
        if constexpr (BF16OUT)
          outB[(size_t)m * ldo + n] = f2bf(v);
        else
          outF[(size_t)m * ldo + n] = v;
      }
    }
}

// ---------------- K4: out = z3b @ de_emb^T + de_bias ------------------------
// No-staging variant: B-fragments are read DIRECTLY from global de_emb
// (cached; each line reused 4x by the 4 wM waves via L1/L2) and converted
// f32->bf16 with v_cvt_pk_bf16_f32 in-loop. LDS = 16 KB Cs only -> no
// staging phase/barrier, no Bs bank conflicts. Epilogue identical to R10:
// dbuf Cs, lgkm-only barriers, nt full-line 512B/row stores.
__global__ __launch_bounds__(512)
void k4_decode(const unsigned short* __restrict__ z3b,  // [512][256] bf16
               const float* __restrict__ de_emb,        // [NEMB][256]
               const float* __restrict__ de_bias,       // [NEMB]
               float* __restrict__ out) {               // [512][NEMB]
  __shared__ __align__(16) float Cs[2][16 * 128];     // 16 KB dbuf, XOR-swz

  const int n0 = blockIdx.x * TILE_N;
  const int tid = threadIdx.x;
  const int lane = tid & 63, wave = tid >> 6;  // 8 waves
  const int wM = wave >> 1, wN = wave & 1;     // 4(M) x 2(N)
  const int g = lane >> 4, r16 = lane & 15;

  // per-lane B row pointers (clamped for tail block; bad rows masked at store)
  const float* brow[4];
#pragma unroll
  for (int fn = 0; fn < 4; ++fn) {
    int r = n0 + wN * 64 + fn * 16 + r16;
    if (r > NEMB - 1) r = NEMB - 1;
    brow[fn] = de_emb + (size_t)r * EMBD;
  }

  f32x4 biasv[4];
#pragma unroll
  for (int fn = 0; fn < 4; ++fn) {
    const int n = n0 + wN * 64 + fn * 16 + g * 4;
    if (n < NEMB) biasv[fn] = *(const f32x4*)(de_bias + n);
    else { biasv[fn][0] = biasv[fn][1] = biasv[fn][2] = biasv[fn][3] = 0.f; }
  }

  // store-side lane mapping (full-line 512B row segments)
  const int srow = tid >> 5;         // 0..15
  const int scol = (tid & 31) * 4;   // 0..124

  const f32x4 z4 = {0.f, 0.f, 0.f, 0.f};
  for (int mc = 0; mc < 4; ++mc) {
    f32x4 acc[4][2];  // [fn][fm]
#pragma unroll
    for (int a = 0; a < 4; ++a)
#pragma unroll
      for (int b = 0; b < 2; ++b) acc[a][b] = z4;

#pragma unroll
    for (int kk = 0; kk < 8; ++kk) {
      bf16x8 a[2];
#pragma unroll
      for (int fm = 0; fm < 2; ++fm) {
        const int m = mc * 128 + wM * 32 + fm * 16 + r16;
        a[fm] = *(const bf16x8*)(z3b + (size_t)m * EMBD + kk * 32 + g * 8);
      }
#pragma unroll
      for (int fn = 0; fn < 4; ++fn) {
        const float* p = brow[fn] + kk * 32 + g * 8;
        const f32x4 x = *(const f32x4*)p;
        const f32x4 y = *(const f32x4*)(p + 4);
        const bf16x8 b = cvt8(x, y);
#pragma unroll
        for (int fm = 0; fm < 2; ++fm)
          acc[fn][fm] = __builtin_amdgcn_mfma_f32_16x16x32_bf16(b, a[fm], acc[fn][fm], 0, 0, 0);
      }
    }

    // ---- double-buffered epilogue: raw barriers, NT full-line stores ----
    if (wM == 0) {
#pragma unroll
      for (int fn = 0; fn < 4; ++fn) {
        const int nl = wN * 64 + fn * 16 + g * 4;
        *(f32x4*)(&Cs[0][r16 * 128 + (nl ^ ((r16 & 7) << 2))]) = acc[fn][0] + biasv[fn];
      }
    }
    barrier_lgkm();
#pragma unroll
    for (int h = 0; h < 8; ++h) {
      if (h < 7 && wM == ((h + 1) >> 1)) {
        const int fm = (h + 1) & 1;
#pragma unroll
        for (int fn = 0; fn < 4; ++fn) {
          const int nl = wN * 64 + fn * 16 + g * 4;
          *(f32x4*)(&Cs[(h + 1) & 1][r16 * 128 + (nl ^ ((r16 & 7) << 2))]) =
              acc[fn][fm] + biasv[fn];
        }
      }
      // stream 16 rows x 512B (full lines) from buf h&1 — NON-TEMPORAL
      const int n = n0 + scol;
      if (n < NEMB) {
        const int m = mc * 128 + h * 16 + srow;
        const f32x4 v = *(const f32x4*)(&Cs[h & 1][srow * 128 + (scol ^ ((srow & 7) << 2))]);
        __builtin_nontemporal_store(v, (f32x4*)(out + (size_t)m * NEMB + n));
      }
      barrier_lgkm();
    }
  }
}

extern "C" void kernel_launch(void* const* d_in, const int* in_sizes, int n_in,
                              void* d_out, int out_size, void* d_ws, size_t ws_size,
                              hipStream_t stream) {
  (void)in_sizes; (void)n_in; (void)out_size;
  const float* rin     = (const float*)d_in[0];
  const int*   act     = (const int*)d_in[1];
  const float* en_emb  = (const float*)d_in[2];
  const float* en_bias = (const float*)d_in[3];
  const float* enc_W   = (const float*)d_in[4];
  const float* enc_b   = (const float*)d_in[5];
  const float* dec_W   = (const float*)d_in[6];
  const float* dec_b   = (const float*)d_in[7];
  const float* de_emb  = (const float*)d_in[8];
  const float* de_bias = (const float*)d_in[9];
  float* out = (float*)d_out;

  // ws layout (bytes): part | z1 | z2 | z3b | wactP
  float* ws   = (float*)d_ws;
  float* part = ws;
  float* z1   = part + (size_t)SPLITS * (B_ * EMBD);
  float* z2   = z1 + (size_t)B_ * EMBD;
  unsigned short* z3b = (unsigned short*)(z2 + (size_t)B_ * HIDD);
  unsigned short* wactP = z3b + (size_t)B_ * EMBD;
  const size_t need = ((size_t)SPLITS * B_ * EMBD + B_ * EMBD + B_ * HIDD) * 4
                      + (size_t)B_ * EMBD * 2 + (size_t)KD * EMBD * 2;

  if (ws_size >= need) {
    k0_pack<<<dim3(KD / 8), 256, 0, stream>>>(act, en_emb, wactP);
    k1_dense<<<dim3(4, 2, SPLITS), 512, 0, stream>>>(rin, wactP, part);
  } else {
    k1_gather_gemm<<<dim3(8, 4, SPLITS), 256, 0, stream>>>(rin, act, en_emb, part);
  }
  k1_reduce<<<dim3((B_ * EMBD) / 256), 256, 0, stream>>>(part, en_bias, z1);
  mlp_gemm<EMBD, EMBD, EMBD, false><<<dim3(8, 8), 256, 0, stream>>>(z1, enc_W, enc_b, z2, nullptr, HIDD);
  mlp_gemm<HIDD, HIDD, HIDD, true><<<dim3(8, 4), 256, 0, stream>>>(z2, dec_W, dec_b, nullptr, z3b, EMBD);
  k4_decode<<<dim3((NEMB + TILE_N - 1) / TILE_N), 512, 0, stream>>>(z3b, de_emb, de_bias, out);
}

// Round 12
// 269.182 us; speedup vs baseline: 2.2278x; 2.2278x over previous
//
#include <hip/hip_runtime.h>

#define B_    512
#define KD    20000
#define EMBD  256
#define HIDD  512
#define NEMB  200000
#define SPLITS 25
#define KSPAN  800   // 20000 / 25, = 25 k-steps of 32
#define TILE_N 128   // k4 n-panel per block -> 512B per out row per block

typedef __attribute__((ext_vector_type(8))) short bf16x8;
typedef __attribute__((ext_vector_type(4))) float f32x4;
typedef __attribute__((ext_vector_type(8))) unsigned short u16x8;

__device__ __forceinline__ unsigned short f2bf(float f) {
  unsigned int u = __float_as_uint(f);
  return (unsigned short)((u + 0x7fffu + ((u >> 16) & 1u)) >> 16);  // RNE
}

__device__ __forceinline__ float selu_f(float x) {
  const float kScale = 1.0507009873554805f;
  const float kSA    = 1.7580993408473766f;  // scale*alpha
  return x > 0.0f ? kScale * x : kSA * (__expf(x) - 1.0f);
}

// raw barrier: LDS-visibility only (lgkmcnt), does NOT drain vmcnt ->
// global (nt) stores stay in flight across substeps.
__device__ __forceinline__ void barrier_lgkm() {
  asm volatile("s_waitcnt lgkmcnt(0)" ::: "memory");
  __builtin_amdgcn_s_barrier();
  __builtin_amdgcn_sched_barrier(0);
}

// load 8 consecutive f32 and pack to bf16x8 (16B-aligned source)
__device__ __forceinline__ bf16x8 load8f(const float* __restrict__ p) {
  float4 a = *(const float4*)p;
  float4 b = *(const float4*)(p + 4);
  bf16x8 r;
  r[0] = (short)f2bf(a.x); r[1] = (short)f2bf(a.y);
  r[2] = (short)f2bf(a.z); r[3] = (short)f2bf(a.w);
  r[4] = (short)f2bf(b.x); r[5] = (short)f2bf(b.y);
  r[6] = (short)f2bf(b.z); r[7] = (short)f2bf(b.w);
  return r;
}

// ---------------- K0: gather+pack en_emb[act] -> wactP[k/8][e=256][8] bf16 --
__global__ void k0_pack(const int* __restrict__ act,
                        const float* __restrict__ en_emb,
                        unsigned short* __restrict__ wactP) {
  const int tid = threadIdx.x;       // = e (0..255)
  const int k0 = blockIdx.x * 8;
  const int is64 = ((act[1] | act[3] | act[5] | act[7]) == 0) ? 1 : 0;
  int idx[8];
#pragma unroll
  for (int j = 0; j < 8; ++j)
    idx[j] = is64 ? act[(size_t)(k0 + j) * 2] : act[k0 + j];
  u16x8 v;
#pragma unroll
  for (int j = 0; j < 8; ++j)
    v[j] = f2bf(en_emb[(size_t)idx[j] * EMBD + tid]);
  *(u16x8*)(wactP + (size_t)k0 * EMBD + tid * 8) = v;
}

// ---------------- K1 (packed): split-K dense GEMM: part[kz] += rin @ wactP --
// grid (4,2,25), 512 thr (8 waves 4Mx2N), block tile 128m x 128n:
// rin read exactly ONCE from HBM, wactP duplication 4x. (validated R11)
__global__ __launch_bounds__(512)
void k1_dense(const float* __restrict__ rin,
              const unsigned short* __restrict__ wactP,
              float* __restrict__ part) {
  const int tid = threadIdx.x;
  const int lane = tid & 63, wave = tid >> 6;
  const int wM = wave >> 1, wN = wave & 1;   // 4(M) x 2(N)
  const int g = lane >> 4, r16 = lane & 15;
  const int m0 = blockIdx.x * 128 + wM * 32;
  const int n0 = blockIdx.y * 128 + wN * 64;
  const int kz = blockIdx.z;

  const f32x4 z4 = {0.f, 0.f, 0.f, 0.f};
  f32x4 acc[2][4];  // [fm][fn]
#pragma unroll
  for (int a = 0; a < 2; ++a)
#pragma unroll
    for (int b = 0; b < 4; ++b) acc[a][b] = z4;

  for (int s = 0; s < 25; ++s) {
    const int kb = kz * KSPAN + s * 32 + g * 8;
    bf16x8 afr[2], bfr[4];
#pragma unroll
    for (int fm = 0; fm < 2; ++fm)
      afr[fm] = load8f(rin + (size_t)(m0 + fm * 16 + r16) * KD + kb);
#pragma unroll
    for (int fn = 0; fn < 4; ++fn) {
      const int e = n0 + fn * 16 + r16;
      bfr[fn] = *(const bf16x8*)(wactP + (size_t)(kb >> 3) * (EMBD * 8) + e * 8);
    }
#pragma unroll
    for (int fm = 0; fm < 2; ++fm)
#pragma unroll
      for (int fn = 0; fn < 4; ++fn)
        acc[fm][fn] = __builtin_amdgcn_mfma_f32_16x16x32_bf16(afr[fm], bfr[fn], acc[fm][fn], 0, 0, 0);
  }
  float* pz = part + (size_t)kz * (B_ * EMBD);
#pragma unroll
  for (int fm = 0; fm < 2; ++fm)
#pragma unroll
    for (int fn = 0; fn < 4; ++fn) {
      const int n = n0 + fn * 16 + r16;
#pragma unroll
      for (int j = 0; j < 4; ++j) {
        const int m = m0 + fm * 16 + g * 4 + j;
        pz[(size_t)m * EMBD + n] = acc[fm][fn][j];
      }
    }
}

// ---------------- K1 (fallback, gather in-loop) -----------------------------
__global__ void k1_gather_gemm(const float* __restrict__ rin,
                               const int* __restrict__ act,
                               const float* __restrict__ en_emb,
                               float* __restrict__ part) {
  const int tid = threadIdx.x;
  const int lane = tid & 63, wave = tid >> 6;
  const int wm = wave >> 1, wn = wave & 1;
  const int g = lane >> 4, r16 = lane & 15;
  const int m0 = blockIdx.x * 64 + wm * 32;
  const int n0 = blockIdx.y * 64 + wn * 32;
  const int kz = blockIdx.z;
  const int is64 = ((act[1] | act[3] | act[5] | act[7]) == 0) ? 1 : 0;

  const f32x4 z4 = {0.f, 0.f, 0.f, 0.f};
  f32x4 acc[2][2];
#pragma unroll
  for (int a = 0; a < 2; ++a)
#pragma unroll
    for (int b = 0; b < 2; ++b) acc[a][b] = z4;

  for (int s = 0; s < 25; ++s) {
    const int k = kz * KSPAN + s * 32;
    const int kb = k + g * 8;
    bf16x8 afr[2];
#pragma unroll
    for (int fm = 0; fm < 2; ++fm)
      afr[fm] = load8f(rin + (size_t)(m0 + fm * 16 + r16) * KD + kb);
    int idx8[8];
#pragma unroll
    for (int j = 0; j < 8; ++j)
      idx8[j] = is64 ? act[(size_t)(kb + j) * 2] : act[kb + j];
    bf16x8 bfr[2];
#pragma unroll
    for (int fn = 0; fn < 2; ++fn) {
      const int e = n0 + fn * 16 + r16;
#pragma unroll
      for (int j = 0; j < 8; ++j)
        bfr[fn][j] = (short)f2bf(en_emb[(size_t)idx8[j] * EMBD + e]);
    }
#pragma unroll
    for (int fm = 0; fm < 2; ++fm)
#pragma unroll
      for (int fn = 0; fn < 2; ++fn)
        acc[fm][fn] = __builtin_amdgcn_mfma_f32_16x16x32_bf16(afr[fm], bfr[fn], acc[fm][fn], 0, 0, 0);
  }
  float* pz = part + (size_t)kz * (B_ * EMBD);
#pragma unroll
  for (int fm = 0; fm < 2; ++fm)
#pragma unroll
    for (int fn = 0; fn < 2; ++fn) {
      const int n = n0 + fn * 16 + r16;
#pragma unroll
      for (int j = 0; j < 4; ++j) {
        const int m = m0 + fm * 16 + g * 4 + j;
        pz[(size_t)m * EMBD + n] = acc[fm][fn][j];
      }
    }
}

// ---------------- K1b: reduce splits + bias + selu -> z1 (f32) --------------
__global__ void k1_reduce(const float* __restrict__ part,
                          const float* __restrict__ en_bias,
                          float* __restrict__ z1) {
  const int i = blockIdx.x * blockDim.x + threadIdx.x;
  float s = 0.f;
#pragma unroll
  for (int p = 0; p < SPLITS; ++p) s += part[(size_t)p * (B_ * EMBD) + i];
  z1[i] = selu_f(s + en_bias[i & (EMBD - 1)]);
}

// ---------------- K2/K3: small MLP GEMM (C = A @ Bw^T), register-only -------
template <int KDIM, int LDA, int LDB, bool BF16OUT>
__global__ void mlp_gemm(const float* __restrict__ A,
                         const float* __restrict__ Bw,
                         const float* __restrict__ bias,
                         float* __restrict__ outF,
                         unsigned short* __restrict__ outB,
                         int ldo) {
  const int tid = threadIdx.x;
  const int lane = tid & 63, wave = tid >> 6;
  const int wm = wave >> 1, wn = wave & 1;
  const int g = lane >> 4, r16 = lane & 15;
  const int m0 = blockIdx.x * 64 + wm * 32;
  const int n0 = blockIdx.y * 64 + wn * 32;

  const f32x4 z4 = {0.f, 0.f, 0.f, 0.f};
  f32x4 acc[2][2];
#pragma unroll
  for (int a = 0; a < 2; ++a)
#pragma unroll
    for (int b = 0; b < 2; ++b) acc[a][b] = z4;

#pragma unroll
  for (int k = 0; k < KDIM; k += 32) {
    const int kb = k + g * 8;
    bf16x8 afr[2], bfr[2];
#pragma unroll
    for (int fm = 0; fm < 2; ++fm)
      afr[fm] = load8f(A + (size_t)(m0 + fm * 16 + r16) * LDA + kb);
#pragma unroll
    for (int fn = 0; fn < 2; ++fn)
      bfr[fn] = load8f(Bw + (size_t)(n0 + fn * 16 + r16) * LDB + kb);
#pragma unroll
    for (int fm = 0; fm < 2; ++fm)
#pragma unroll
      for (int fn = 0; fn < 2; ++fn)
        acc[fm][fn] = __builtin_amdgcn_mfma_f32_16x16x32_bf16(afr[fm], bfr[fn], acc[fm][fn], 0, 0, 0);
  }
#pragma unroll
  for (int fm = 0; fm < 2; ++fm)
#pragma unroll
    for (int fn = 0; fn < 2; ++fn) {
      const int n = n0 + fn * 16 + r16;
      const float bv = bias[n];
#pragma unroll
      for (int j = 0; j < 4; ++j) {
        const int m = m0 + fm * 16 + g * 4 + j;
        const float v = selu_f(acc[fm][fn][j] + bv);
        if constexpr (BF16OUT)
          outB[(size_t)m * ldo + n] = f2bf(v);
        else
          outF[(size_t)m * ldo + n] = v;
      }
    }
}

// ---------------- K4: out = z3b @ de_emb^T + de_bias ------------------------
// R10 structure (best: 265.7us total): Bs nt-staged + swizzled, dbuf Cs,
// lgkm-only barriers, NT full-line 512B/row stores. R12 single delta:
// half A-prefetch — next mc's kk=0..3 z3b fragments loaded into VGPRs
// BEFORE the epilogue's nt stores enter the vmcnt queue, so the next
// K-loop's first half never waits behind the store drain (in-order vmcnt).
// __launch_bounds__(512,4) pins VGPR <= 128 -> 2 blocks/CU preserved.
__global__ __launch_bounds__(512, 4)
void k4_decode(const unsigned short* __restrict__ z3b,  // [512][256] bf16
               const float* __restrict__ de_emb,        // [NEMB][256]
               const float* __restrict__ de_bias,       // [NEMB]
               float* __restrict__ out) {               // [512][NEMB]
  __shared__ unsigned short Bs[TILE_N * 256];         // 64 KB, swizzled bf16
  __shared__ __align__(16) float Cs[2][16 * 128];     // 16 KB dbuf, XOR-swz

  const int n0 = blockIdx.x * TILE_N;
  const int tid = threadIdx.x;

  // ---- stage de_emb tile -> Bs (bf16, swizzled); NT loads (single-use) ----
  {
    const int sr = tid >> 2, sq = tid & 3;  // row 0..127, k-quarter 0..3
    const int nrow = n0 + sr;
    const float* src = de_emb + (size_t)nrow * EMBD;
#pragma unroll
    for (int i = 0; i < 8; ++i) {
      const int k0 = i * 32 + sq * 8;
      u16x8 v;
      if (nrow < NEMB) {
        f32x4 x = __builtin_nontemporal_load((const f32x4*)(src + k0));
        f32x4 y = __builtin_nontemporal_load((const f32x4*)(src + k0 + 4));
        v[0] = f2bf(x[0]); v[1] = f2bf(x[1]); v[2] = f2bf(x[2]); v[3] = f2bf(x[3]);
        v[4] = f2bf(y[0]); v[5] = f2bf(y[1]); v[6] = f2bf(y[2]); v[7] = f2bf(y[3]);
      } else {
#pragma unroll
        for (int t = 0; t < 8; ++t) v[t] = 0;
      }
      const int sidx = sr * 256 + (k0 ^ ((sr & 7) << 3));
      *(u16x8*)(&Bs[sidx]) = v;
    }
  }

  const int lane = tid & 63, wave = tid >> 6;  // 8 waves
  const int wM = wave >> 1, wN = wave & 1;     // 4(M) x 2(N)
  const int g = lane >> 4, r16 = lane & 15;

  // prefill A-prefetch for mc=0, kk=0..3 (issued before the staging barrier;
  // overlaps the staging drain)
  bf16x8 Apf[2][4];
#pragma unroll
  for (int kk = 0; kk < 4; ++kk)
#pragma unroll
    for (int fm = 0; fm < 2; ++fm) {
      const int m = wM * 32 + fm * 16 + r16;
      Apf[fm][kk] = *(const bf16x8*)(z3b + (size_t)m * EMBD + kk * 32 + g * 8);
    }

  __syncthreads();  // one-time (staging visibility)

  f32x4 biasv[4];
#pragma unroll
  for (int fn = 0; fn < 4; ++fn) {
    const int n = n0 + wN * 64 + fn * 16 + g * 4;
    if (n < NEMB) biasv[fn] = *(const f32x4*)(de_bias + n);
    else { biasv[fn][0] = biasv[fn][1] = biasv[fn][2] = biasv[fn][3] = 0.f; }
  }

  // store-side lane mapping (full-line 512B row segments)
  const int srow = tid >> 5;         // 0..15
  const int scol = (tid & 31) * 4;   // 0..124

  const f32x4 z4 = {0.f, 0.f, 0.f, 0.f};
  for (int mc = 0; mc < 4; ++mc) {
    f32x4 acc[4][2];  // [fn][fm]
#pragma unroll
    for (int a = 0; a < 4; ++a)
#pragma unroll
      for (int b = 0; b < 2; ++b) acc[a][b] = z4;

#pragma unroll
    for (int kk = 0; kk < 8; ++kk) {
      bf16x8 a[2];
#pragma unroll
      for (int fm = 0; fm < 2; ++fm) {
        if (kk < 4) {
          a[fm] = Apf[fm][kk];
        } else {
          const int m = mc * 128 + wM * 32 + fm * 16 + r16;
          a[fm] = *(const bf16x8*)(z3b + (size_t)m * EMBD + kk * 32 + g * 8);
        }
      }
#pragma unroll
      for (int fn = 0; fn < 4; ++fn) {
        const int rr = wN * 64 + fn * 16 + r16;
        const int koff = (kk * 32 + g * 8) ^ ((rr & 7) << 3);
        const bf16x8 b = *(const bf16x8*)(&Bs[rr * 256 + koff]);
#pragma unroll
        for (int fm = 0; fm < 2; ++fm)
          acc[fn][fm] = __builtin_amdgcn_mfma_f32_16x16x32_bf16(b, a[fm], acc[fn][fm], 0, 0, 0);
      }
    }

    // prefetch next mc's first-half A-fragments BEFORE the epilogue stores
    if (mc < 3) {
#pragma unroll
      for (int kk = 0; kk < 4; ++kk)
#pragma unroll
        for (int fm = 0; fm < 2; ++fm) {
          const int m = (mc + 1) * 128 + wM * 32 + fm * 16 + r16;
          Apf[fm][kk] = *(const bf16x8*)(z3b + (size_t)m * EMBD + kk * 32 + g * 8);
        }
    }

    // ---- double-buffered epilogue: raw barriers, NT full-line stores ----
    if (wM == 0) {
#pragma unroll
      for (int fn = 0; fn < 4; ++fn) {
        const int nl = wN * 64 + fn * 16 + g * 4;
        *(f32x4*)(&Cs[0][r16 * 128 + (nl ^ ((r16 & 7) << 2))]) = acc[fn][0] + biasv[fn];
      }
    }
    barrier_lgkm();
#pragma unroll
    for (int h = 0; h < 8; ++h) {
      if (h < 7 && wM == ((h + 1) >> 1)) {
        const int fm = (h + 1) & 1;
#pragma unroll
        for (int fn = 0; fn < 4; ++fn) {
          const int nl = wN * 64 + fn * 16 + g * 4;
          *(f32x4*)(&Cs[(h + 1) & 1][r16 * 128 + (nl ^ ((r16 & 7) << 2))]) =
              acc[fn][fm] + biasv[fn];
        }
      }
      // stream 16 rows x 512B (full lines) from buf h&1 — NON-TEMPORAL
      const int n = n0 + scol;
      if (n < NEMB) {
        const int m = mc * 128 + h * 16 + srow;
        const f32x4 v = *(const f32x4*)(&Cs[h & 1][srow * 128 + (scol ^ ((srow & 7) << 2))]);
        __builtin_nontemporal_store(v, (f32x4*)(out + (size_t)m * NEMB + n));
      }
      barrier_lgkm();
    }
  }
}

extern "C" void kernel_launch(void* const* d_in, const int* in_sizes, int n_in,
                              void* d_out, int out_size, void* d_ws, size_t ws_size,
                              hipStream_t stream) {
  (void)in_sizes; (void)n_in; (void)out_size;
  const float* rin     = (const float*)d_in[0];
  const int*   act     = (const int*)d_in[1];
  const float* en_emb  = (const float*)d_in[2];
  const float* en_bias = (const float*)d_in[3];
  const float* enc_W   = (const float*)d_in[4];
  const float* enc_b   = (const float*)d_in[5];
  const float* dec_W   = (const float*)d_in[6];
  const float* dec_b   = (const float*)d_in[7];
  const float* de_emb  = (const float*)d_in[8];
  const float* de_bias = (const float*)d_in[9];
  float* out = (float*)d_out;

  // ws layout (bytes): part | z1 | z2 | z3b | wactP
  float* ws   = (float*)d_ws;
  float* part = ws;
  float* z1   = part + (size_t)SPLITS * (B_ * EMBD);
  float* z2   = z1 + (size_t)B_ * EMBD;
  unsigned short* z3b = (unsigned short*)(z2 + (size_t)B_ * HIDD);
  unsigned short* wactP = z3b + (size_t)B_ * EMBD;
  const size_t need = ((size_t)SPLITS * B_ * EMBD + B_ * EMBD + B_ * HIDD) * 4
                      + (size_t)B_ * EMBD * 2 + (size_t)KD * EMBD * 2;

  if (ws_size >= need) {
    k0_pack<<<dim3(KD / 8), 256, 0, stream>>>(act, en_emb, wactP);
    k1_dense<<<dim3(4, 2, SPLITS), 512, 0, stream>>>(rin, wactP, part);
  } else {
    k1_gather_gemm<<<dim3(8, 4, SPLITS), 256, 0, stream>>>(rin, act, en_emb, part);
  }
  k1_reduce<<<dim3((B_ * EMBD) / 256), 256, 0, stream>>>(part, en_bias, z1);
  mlp_gemm<EMBD, EMBD, EMBD, false><<<dim3(8, 8), 256, 0, stream>>>(z1, enc_W, enc_b, z2, nullptr, HIDD);
  mlp_gemm<HIDD, HIDD, HIDD, true><<<dim3(8, 4), 256, 0, stream>>>(z2, dec_W, dec_b, nullptr, z3b, EMBD);
  k4_decode<<<dim3((NEMB + TILE_N - 1) / TILE_N), 512, 0, stream>>>(z3b, de_emb, de_bias, out);
}

// Round 13
// 267.892 us; speedup vs baseline: 2.2385x; 1.0048x over previous
//
#include <hip/hip_runtime.h>

#define B_    512
#define KD    20000
#define EMBD  256
#define HIDD  512
#define NEMB  200000
#define SPLITS 25
#define KSPAN  800   // 20000 / 25, = 25 k-steps of 32
#define TILE_N 128   // k4 n-panel per block -> 512B per out row per block

typedef __attribute__((ext_vector_type(8))) short bf16x8;
typedef __attribute__((ext_vector_type(4))) float f32x4;
typedef __attribute__((ext_vector_type(8))) unsigned short u16x8;

__device__ __forceinline__ unsigned short f2bf(float f) {
  unsigned int u = __float_as_uint(f);
  return (unsigned short)((u + 0x7fffu + ((u >> 16) & 1u)) >> 16);  // RNE
}

__device__ __forceinline__ float selu_f(float x) {
  const float kScale = 1.0507009873554805f;
  const float kSA    = 1.7580993408473766f;  // scale*alpha
  return x > 0.0f ? kScale * x : kSA * (__expf(x) - 1.0f);
}

// raw barrier: LDS-visibility only (lgkmcnt), does NOT drain vmcnt ->
// global (nt) stores stay in flight across substeps.
__device__ __forceinline__ void barrier_lgkm() {
  asm volatile("s_waitcnt lgkmcnt(0)" ::: "memory");
  __builtin_amdgcn_s_barrier();
  __builtin_amdgcn_sched_barrier(0);
}

// load 8 consecutive f32 and pack to bf16x8 (16B-aligned source)
__device__ __forceinline__ bf16x8 load8f(const float* __restrict__ p) {
  float4 a = *(const float4*)p;
  float4 b = *(const float4*)(p + 4);
  bf16x8 r;
  r[0] = (short)f2bf(a.x); r[1] = (short)f2bf(a.y);
  r[2] = (short)f2bf(a.z); r[3] = (short)f2bf(a.w);
  r[4] = (short)f2bf(b.x); r[5] = (short)f2bf(b.y);
  r[6] = (short)f2bf(b.z); r[7] = (short)f2bf(b.w);
  return r;
}

// ---------------- K0: gather+pack en_emb[act] -> wactP[k/8][e=256][8] bf16 --
__global__ void k0_pack(const int* __restrict__ act,
                        const float* __restrict__ en_emb,
                        unsigned short* __restrict__ wactP) {
  const int tid = threadIdx.x;       // = e (0..255)
  const int k0 = blockIdx.x * 8;
  const int is64 = ((act[1] | act[3] | act[5] | act[7]) == 0) ? 1 : 0;
  int idx[8];
#pragma unroll
  for (int j = 0; j < 8; ++j)
    idx[j] = is64 ? act[(size_t)(k0 + j) * 2] : act[k0 + j];
  u16x8 v;
#pragma unroll
  for (int j = 0; j < 8; ++j)
    v[j] = f2bf(en_emb[(size_t)idx[j] * EMBD + tid]);
  *(u16x8*)(wactP + (size_t)k0 * EMBD + tid * 8) = v;
}

// ---------------- K1 (packed): split-K dense GEMM: part[kz] += rin @ wactP --
// grid (8,4,25), block 256 (4 waves, 2x2), tile 64x64 (R10 configuration)
__global__ void k1_dense(const float* __restrict__ rin,
                         const unsigned short* __restrict__ wactP,
                         float* __restrict__ part) {
  const int tid = threadIdx.x;
  const int lane = tid & 63, wave = tid >> 6;
  const int wm = wave >> 1, wn = wave & 1;
  const int g = lane >> 4, r16 = lane & 15;
  const int m0 = blockIdx.x * 64 + wm * 32;
  const int n0 = blockIdx.y * 64 + wn * 32;
  const int kz = blockIdx.z;

  const f32x4 z4 = {0.f, 0.f, 0.f, 0.f};
  f32x4 acc[2][2];
#pragma unroll
  for (int a = 0; a < 2; ++a)
#pragma unroll
    for (int b = 0; b < 2; ++b) acc[a][b] = z4;

  for (int s = 0; s < 25; ++s) {
    const int kb = kz * KSPAN + s * 32 + g * 8;
    bf16x8 afr[2], bfr[2];
#pragma unroll
    for (int fm = 0; fm < 2; ++fm)
      afr[fm] = load8f(rin + (size_t)(m0 + fm * 16 + r16) * KD + kb);
#pragma unroll
    for (int fn = 0; fn < 2; ++fn) {
      const int e = n0 + fn * 16 + r16;
      bfr[fn] = *(const bf16x8*)(wactP + (size_t)(kb >> 3) * (EMBD * 8) + e * 8);
    }
#pragma unroll
    for (int fm = 0; fm < 2; ++fm)
#pragma unroll
      for (int fn = 0; fn < 2; ++fn)
        acc[fm][fn] = __builtin_amdgcn_mfma_f32_16x16x32_bf16(afr[fm], bfr[fn], acc[fm][fn], 0, 0, 0);
  }
  float* pz = part + (size_t)kz * (B_ * EMBD);
#pragma unroll
  for (int fm = 0; fm < 2; ++fm)
#pragma unroll
    for (int fn = 0; fn < 2; ++fn) {
      const int n = n0 + fn * 16 + r16;
#pragma unroll
      for (int j = 0; j < 4; ++j) {
        const int m = m0 + fm * 16 + g * 4 + j;
        pz[(size_t)m * EMBD + n] = acc[fm][fn][j];
      }
    }
}

// ---------------- K1 (fallback, gather in-loop) -----------------------------
__global__ void k1_gather_gemm(const float* __restrict__ rin,
                               const int* __restrict__ act,
                               const float* __restrict__ en_emb,
                               float* __restrict__ part) {
  const int tid = threadIdx.x;
  const int lane = tid & 63, wave = tid >> 6;
  const int wm = wave >> 1, wn = wave & 1;
  const int g = lane >> 4, r16 = lane & 15;
  const int m0 = blockIdx.x * 64 + wm * 32;
  const int n0 = blockIdx.y * 64 + wn * 32;
  const int kz = blockIdx.z;
  const int is64 = ((act[1] | act[3] | act[5] | act[7]) == 0) ? 1 : 0;

  const f32x4 z4 = {0.f, 0.f, 0.f, 0.f};
  f32x4 acc[2][2];
#pragma unroll
  for (int a = 0; a < 2; ++a)
#pragma unroll
    for (int b = 0; b < 2; ++b) acc[a][b] = z4;

  for (int s = 0; s < 25; ++s) {
    const int kb = kz * KSPAN + s * 32 + g * 8;
    bf16x8 afr[2];
#pragma unroll
    for (int fm = 0; fm < 2; ++fm)
      afr[fm] = load8f(rin + (size_t)(m0 + fm * 16 + r16) * KD + kb);
    int idx8[8];
#pragma unroll
    for (int j = 0; j < 8; ++j)
      idx8[j] = is64 ? act[(size_t)(kb + j) * 2] : act[kb + j];
    bf16x8 bfr[2];
#pragma unroll
    for (int fn = 0; fn < 2; ++fn) {
      const int e = n0 + fn * 16 + r16;
#pragma unroll
      for (int j = 0; j < 8; ++j)
        bfr[fn][j] = (short)f2bf(en_emb[(size_t)idx8[j] * EMBD + e]);
    }
#pragma unroll
    for (int fm = 0; fm < 2; ++fm)
#pragma unroll
      for (int fn = 0; fn < 2; ++fn)
        acc[fm][fn] = __builtin_amdgcn_mfma_f32_16x16x32_bf16(afr[fm], bfr[fn], acc[fm][fn], 0, 0, 0);
  }
  float* pz = part + (size_t)kz * (B_ * EMBD);
#pragma unroll
  for (int fm = 0; fm < 2; ++fm)
#pragma unroll
    for (int fn = 0; fn < 2; ++fn) {
      const int n = n0 + fn * 16 + r16;
#pragma unroll
      for (int j = 0; j < 4; ++j) {
        const int m = m0 + fm * 16 + g * 4 + j;
        pz[(size_t)m * EMBD + n] = acc[fm][fn][j];
      }
    }
}

// ---------------- K1b: reduce splits + bias + selu -> z1 (f32) --------------
__global__ void k1_reduce(const float* __restrict__ part,
                          const float* __restrict__ en_bias,
                          float* __restrict__ z1) {
  const int i = blockIdx.x * blockDim.x + threadIdx.x;
  float s = 0.f;
#pragma unroll
  for (int p = 0; p < SPLITS; ++p) s += part[(size_t)p * (B_ * EMBD) + i];
  z1[i] = selu_f(s + en_bias[i & (EMBD - 1)]);
}

// ---------------- K2/K3: small MLP GEMM (C = A @ Bw^T), register-only -------
template <int KDIM, int LDA, int LDB, bool BF16OUT>
__global__ void mlp_gemm(const float* __restrict__ A,
                         const float* __restrict__ Bw,
                         const float* __restrict__ bias,
                         float* __restrict__ outF,
                         unsigned short* __restrict__ outB,
                         int ldo) {
  const int tid = threadIdx.x;
  const int lane = tid & 63, wave = tid >> 6;
  const int wm = wave >> 1, wn = wave & 1;
  const int g = lane >> 4, r16 = lane & 15;
  const int m0 = blockIdx.x * 64 + wm * 32;
  const int n0 = blockIdx.y * 64 + wn * 32;

  const f32x4 z4 = {0.f, 0.f, 0.f, 0.f};
  f32x4 acc[2][2];
#pragma unroll
  for (int a = 0; a < 2; ++a)
#pragma unroll
    for (int b = 0; b < 2; ++b) acc[a][b] = z4;

#pragma unroll
  for (int k = 0; k < KDIM; k += 32) {
    const int kb = k + g * 8;
    bf16x8 afr[2], bfr[2];
#pragma unroll
    for (int fm = 0; fm < 2; ++fm)
      afr[fm] = load8f(A + (size_t)(m0 + fm * 16 + r16) * LDA + kb);
#pragma unroll
    for (int fn = 0; fn < 2; ++fn)
      bfr[fn] = load8f(Bw + (size_t)(n0 + fn * 16 + r16) * LDB + kb);
#pragma unroll
    for (int fm = 0; fm < 2; ++fm)
#pragma unroll
      for (int fn = 0; fn < 2; ++fn)
        acc[fm][fn] = __builtin_amdgcn_mfma_f32_16x16x32_bf16(afr[fm], bfr[fn], acc[fm][fn], 0, 0, 0);
  }
#pragma unroll
  for (int fm = 0; fm < 2; ++fm)
#pragma unroll
    for (int fn = 0; fn < 2; ++fn) {
      const int n = n0 + fn * 16 + r16;
      const float bv = bias[n];
#pragma unroll
      for (int j = 0; j < 4; ++j) {
        const int m = m0 + fm * 16 + g * 4 + j;
        const float v = selu_f(acc[fm][fn][j] + bv);
        if constexpr (BF16OUT)
          outB[(size_t)m * ldo + n] = f2bf(v);
        else
          outF[(size_t)m * ldo + n] = v;
      }
    }
}

// ---------------- K4: out = z3b @ de_emb^T + de_bias ------------------------
// R10 structure (best: 265.7us). R13 single delta: 32-row epilogue substeps
// (4 per mc, single-buffer Cs[32][128] = 16 KB) — barriers/mc 9 -> 8 and
// 16 KB of nt stores issued per barrier instead of 8 KB (deeper store
// queue utilization). Write phase: wave pair wM==h writes its full 32-row
// slab (both fm fragments). LDS total 80 KB -> 2 blocks/CU preserved.
__global__ void k4_decode(const unsigned short* __restrict__ z3b,  // [512][256] bf16
                          const float* __restrict__ de_emb,        // [NEMB][256]
                          const float* __restrict__ de_bias,       // [NEMB]
                          float* __restrict__ out) {               // [512][NEMB]
  __shared__ unsigned short Bs[TILE_N * 256];       // 64 KB, swizzled bf16
  __shared__ __align__(16) float Cs[32 * 128];      // 16 KB transpose slab

  const int n0 = blockIdx.x * TILE_N;
  const int tid = threadIdx.x;

  // ---- stage de_emb tile -> Bs (bf16, swizzled); NT loads (single-use) ----
  {
    const int sr = tid >> 2, sq = tid & 3;  // row 0..127, k-quarter 0..3
    const int nrow = n0 + sr;
    const float* src = de_emb + (size_t)nrow * EMBD;
#pragma unroll
    for (int i = 0; i < 8; ++i) {
      const int k0 = i * 32 + sq * 8;
      u16x8 v;
      if (nrow < NEMB) {
        f32x4 x = __builtin_nontemporal_load((const f32x4*)(src + k0));
        f32x4 y = __builtin_nontemporal_load((const f32x4*)(src + k0 + 4));
        v[0] = f2bf(x[0]); v[1] = f2bf(x[1]); v[2] = f2bf(x[2]); v[3] = f2bf(x[3]);
        v[4] = f2bf(y[0]); v[5] = f2bf(y[1]); v[6] = f2bf(y[2]); v[7] = f2bf(y[3]);
      } else {
#pragma unroll
        for (int t = 0; t < 8; ++t) v[t] = 0;
      }
      const int sidx = sr * 256 + (k0 ^ ((sr & 7) << 3));
      *(u16x8*)(&Bs[sidx]) = v;
    }
  }
  __syncthreads();  // one-time

  const int lane = tid & 63, wave = tid >> 6;  // 8 waves
  const int wM = wave >> 1, wN = wave & 1;     // 4(M) x 2(N)
  const int g = lane >> 4, r16 = lane & 15;

  f32x4 biasv[4];
#pragma unroll
  for (int fn = 0; fn < 4; ++fn) {
    const int n = n0 + wN * 64 + fn * 16 + g * 4;
    if (n < NEMB) biasv[fn] = *(const f32x4*)(de_bias + n);
    else { biasv[fn][0] = biasv[fn][1] = biasv[fn][2] = biasv[fn][3] = 0.f; }
  }

  // store-side lane mapping: 32 rows x 512B per substep, 2 f32x4 per thread
  const int srow = tid >> 4;         // 0..31
  const int scol = (tid & 15) * 4;   // 0..60

  const f32x4 z4 = {0.f, 0.f, 0.f, 0.f};
  for (int mc = 0; mc < 4; ++mc) {
    f32x4 acc[4][2];  // [fn][fm]
#pragma unroll
    for (int a = 0; a < 4; ++a)
#pragma unroll
      for (int b = 0; b < 2; ++b) acc[a][b] = z4;

#pragma unroll
    for (int kk = 0; kk < 8; ++kk) {
      bf16x8 a[2];
#pragma unroll
      for (int fm = 0; fm < 2; ++fm) {
        const int m = mc * 128 + wM * 32 + fm * 16 + r16;
        a[fm] = *(const bf16x8*)(z3b + (size_t)m * EMBD + kk * 32 + g * 8);
      }
#pragma unroll
      for (int fn = 0; fn < 4; ++fn) {
        const int rr = wN * 64 + fn * 16 + r16;
        const int koff = (kk * 32 + g * 8) ^ ((rr & 7) << 3);
        const bf16x8 b = *(const bf16x8*)(&Bs[rr * 256 + koff]);
#pragma unroll
        for (int fm = 0; fm < 2; ++fm)
          acc[fn][fm] = __builtin_amdgcn_mfma_f32_16x16x32_bf16(b, a[fm], acc[fn][fm], 0, 0, 0);
      }
    }

    // ---- epilogue: 4 substeps x 32 rows; lgkm barriers, NT full-line ----
#pragma unroll
    for (int h = 0; h < 4; ++h) {
      if (wM == h) {
#pragma unroll
        for (int fm = 0; fm < 2; ++fm)
#pragma unroll
          for (int fn = 0; fn < 4; ++fn) {
            const int lrow = fm * 16 + r16;                 // 0..31
            const int nl = wN * 64 + fn * 16 + g * 4;       // 0..124
            *(f32x4*)(&Cs[lrow * 128 + (nl ^ ((lrow & 7) << 2))]) =
                acc[fn][fm] + biasv[fn];
          }
      }
      barrier_lgkm();
      // stream 32 rows x 512B (full lines) — NON-TEMPORAL, 2 f32x4/thread
      {
        const int m = mc * 128 + h * 32 + srow;
#pragma unroll
        for (int j = 0; j < 2; ++j) {
          const int col = scol + j * 64;
          const int n = n0 + col;
          if (n < NEMB) {
            const f32x4 v = *(const f32x4*)(&Cs[srow * 128 + (col ^ ((srow & 7) << 2))]);
            __builtin_nontemporal_store(v, (f32x4*)(out + (size_t)m * NEMB + n));
          }
        }
      }
      barrier_lgkm();
    }
  }
}

extern "C" void kernel_launch(void* const* d_in, const int* in_sizes, int n_in,
                              void* d_out, int out_size, void* d_ws, size_t ws_size,
                              hipStream_t stream) {
  (void)in_sizes; (void)n_in; (void)out_size;
  const float* rin     = (const float*)d_in[0];
  const int*   act     = (const int*)d_in[1];
  const float* en_emb  = (const float*)d_in[2];
  const float* en_bias = (const float*)d_in[3];
  const float* enc_W   = (const float*)d_in[4];
  const float* enc_b   = (const float*)d_in[5];
  const float* dec_W   = (const float*)d_in[6];
  const float* dec_b   = (const float*)d_in[7];
  const float* de_emb  = (const float*)d_in[8];
  const float* de_bias = (const float*)d_in[9];
  float* out = (float*)d_out;

  // ws layout (bytes): part | z1 | z2 | z3b | wactP
  float* ws   = (float*)d_ws;
  float* part = ws;
  float* z1   = part + (size_t)SPLITS * (B_ * EMBD);
  float* z2   = z1 + (size_t)B_ * EMBD;
  unsigned short* z3b = (unsigned short*)(z2 + (size_t)B_ * HIDD);
  unsigned short* wactP = z3b + (size_t)B_ * EMBD;
  const size_t need = ((size_t)SPLITS * B_ * EMBD + B_ * EMBD + B_ * HIDD) * 4
                      + (size_t)B_ * EMBD * 2 + (size_t)KD * EMBD * 2;

  if (ws_size >= need) {
    k0_pack<<<dim3(KD / 8), 256, 0, stream>>>(act, en_emb, wactP);
    k1_dense<<<dim3(8, 4, SPLITS), 256, 0, stream>>>(rin, wactP, part);
  } else {
    k1_gather_gemm<<<dim3(8, 4, SPLITS), 256, 0, stream>>>(rin, act, en_emb, part);
  }
  k1_reduce<<<dim3((B_ * EMBD) / 256), 256, 0, stream>>>(part, en_bias, z1);
  mlp_gemm<EMBD, EMBD, EMBD, false><<<dim3(8, 8), 256, 0, stream>>>(z1, enc_W, enc_b, z2, nullptr, HIDD);
  mlp_gemm<HIDD, HIDD, HIDD, true><<<dim3(8, 4), 256, 0, stream>>>(z2, dec_W, dec_b, nullptr, z3b, EMBD);
  k4_decode<<<dim3((NEMB + TILE_N - 1) / TILE_N), 512, 0, stream>>>(z3b, de_emb, de_bias, out);
}

// Round 14
// 249.910 us; speedup vs baseline: 2.3996x; 1.0720x over previous
//
#include <hip/hip_runtime.h>

#define B_    512
#define KD    20000
#define EMBD  256
#define HIDD  512
#define NEMB  200000
#define SPLITS 25
#define KSPAN  800   // 20000 / 25, = 25 k-steps of 32
#define TILE_N 128   // k4 n-panel per block -> 512B per out row per block

typedef __attribute__((ext_vector_type(8))) short bf16x8;
typedef __attribute__((ext_vector_type(4))) float f32x4;
typedef __attribute__((ext_vector_type(8))) unsigned short u16x8;

__device__ __forceinline__ unsigned short f2bf(float f) {
  unsigned int u = __float_as_uint(f);
  return (unsigned short)((u + 0x7fffu + ((u >> 16) & 1u)) >> 16);  // RNE
}

__device__ __forceinline__ float selu_f(float x) {
  const float kScale = 1.0507009873554805f;
  const float kSA    = 1.7580993408473766f;  // scale*alpha
  return x > 0.0f ? kScale * x : kSA * (__expf(x) - 1.0f);
}

// raw barrier: LDS-visibility only (lgkmcnt), does NOT drain vmcnt ->
// global (nt) stores stay in flight across substeps.
__device__ __forceinline__ void barrier_lgkm() {
  asm volatile("s_waitcnt lgkmcnt(0)" ::: "memory");
  __builtin_amdgcn_s_barrier();
  __builtin_amdgcn_sched_barrier(0);
}

// load 8 consecutive f32 and pack to bf16x8 (16B-aligned source)
__device__ __forceinline__ bf16x8 load8f(const float* __restrict__ p) {
  float4 a = *(const float4*)p;
  float4 b = *(const float4*)(p + 4);
  bf16x8 r;
  r[0] = (short)f2bf(a.x); r[1] = (short)f2bf(a.y);
  r[2] = (short)f2bf(a.z); r[3] = (short)f2bf(a.w);
  r[4] = (short)f2bf(b.x); r[5] = (short)f2bf(b.y);
  r[6] = (short)f2bf(b.z); r[7] = (short)f2bf(b.w);
  return r;
}

// ---------------- K0: gather+pack en_emb[act] -> wactP[k/8][e=256][8] bf16 --
__global__ void k0_pack(const int* __restrict__ act,
                        const float* __restrict__ en_emb,
                        unsigned short* __restrict__ wactP) {
  const int tid = threadIdx.x;       // = e (0..255)
  const int k0 = blockIdx.x * 8;
  const int is64 = ((act[1] | act[3] | act[5] | act[7]) == 0) ? 1 : 0;
  int idx[8];
#pragma unroll
  for (int j = 0; j < 8; ++j)
    idx[j] = is64 ? act[(size_t)(k0 + j) * 2] : act[k0 + j];
  u16x8 v;
#pragma unroll
  for (int j = 0; j < 8; ++j)
    v[j] = f2bf(en_emb[(size_t)idx[j] * EMBD + tid]);
  *(u16x8*)(wactP + (size_t)k0 * EMBD + tid * 8) = v;
}

// ---------------- K1 (packed): split-K dense GEMM: part[kz] += rin @ wactP --
// grid (4,2,25), 512 thr (8 waves 4Mx2N), block tile 128m x 128n:
// rin read exactly ONCE from HBM (was 4x). Validated standalone in R11
// (upstream 75 -> 64 us).
__global__ __launch_bounds__(512)
void k1_dense(const float* __restrict__ rin,
              const unsigned short* __restrict__ wactP,
              float* __restrict__ part) {
  const int tid = threadIdx.x;
  const int lane = tid & 63, wave = tid >> 6;
  const int wM = wave >> 1, wN = wave & 1;   // 4(M) x 2(N)
  const int g = lane >> 4, r16 = lane & 15;
  const int m0 = blockIdx.x * 128 + wM * 32;
  const int n0 = blockIdx.y * 128 + wN * 64;
  const int kz = blockIdx.z;

  const f32x4 z4 = {0.f, 0.f, 0.f, 0.f};
  f32x4 acc[2][4];  // [fm][fn]
#pragma unroll
  for (int a = 0; a < 2; ++a)
#pragma unroll
    for (int b = 0; b < 4; ++b) acc[a][b] = z4;

  for (int s = 0; s < 25; ++s) {
    const int kb = kz * KSPAN + s * 32 + g * 8;
    bf16x8 afr[2], bfr[4];
#pragma unroll
    for (int fm = 0; fm < 2; ++fm)
      afr[fm] = load8f(rin + (size_t)(m0 + fm * 16 + r16) * KD + kb);
#pragma unroll
    for (int fn = 0; fn < 4; ++fn) {
      const int e = n0 + fn * 16 + r16;
      bfr[fn] = *(const bf16x8*)(wactP + (size_t)(kb >> 3) * (EMBD * 8) + e * 8);
    }
#pragma unroll
    for (int fm = 0; fm < 2; ++fm)
#pragma unroll
      for (int fn = 0; fn < 4; ++fn)
        acc[fm][fn] = __builtin_amdgcn_mfma_f32_16x16x32_bf16(afr[fm], bfr[fn], acc[fm][fn], 0, 0, 0);
  }
  float* pz = part + (size_t)kz * (B_ * EMBD);
#pragma unroll
  for (int fm = 0; fm < 2; ++fm)
#pragma unroll
    for (int fn = 0; fn < 4; ++fn) {
      const int n = n0 + fn * 16 + r16;
#pragma unroll
      for (int j = 0; j < 4; ++j) {
        const int m = m0 + fm * 16 + g * 4 + j;
        pz[(size_t)m * EMBD + n] = acc[fm][fn][j];
      }
    }
}

// ---------------- K1 (fallback, gather in-loop) -----------------------------
__global__ void k1_gather_gemm(const float* __restrict__ rin,
                               const int* __restrict__ act,
                               const float* __restrict__ en_emb,
                               float* __restrict__ part) {
  const int tid = threadIdx.x;
  const int lane = tid & 63, wave = tid >> 6;
  const int wm = wave >> 1, wn = wave & 1;
  const int g = lane >> 4, r16 = lane & 15;
  const int m0 = blockIdx.x * 64 + wm * 32;
  const int n0 = blockIdx.y * 64 + wn * 32;
  const int kz = blockIdx.z;
  const int is64 = ((act[1] | act[3] | act[5] | act[7]) == 0) ? 1 : 0;

  const f32x4 z4 = {0.f, 0.f, 0.f, 0.f};
  f32x4 acc[2][2];
#pragma unroll
  for (int a = 0; a < 2; ++a)
#pragma unroll
    for (int b = 0; b < 2; ++b) acc[a][b] = z4;

  for (int s = 0; s < 25; ++s) {
    const int kb = kz * KSPAN + s * 32 + g * 8;
    bf16x8 afr[2];
#pragma unroll
    for (int fm = 0; fm < 2; ++fm)
      afr[fm] = load8f(rin + (size_t)(m0 + fm * 16 + r16) * KD + kb);
    int idx8[8];
#pragma unroll
    for (int j = 0; j < 8; ++j)
      idx8[j] = is64 ? act[(size_t)(kb + j) * 2] : act[kb + j];
    bf16x8 bfr[2];
#pragma unroll
    for (int fn = 0; fn < 2; ++fn) {
      const int e = n0 + fn * 16 + r16;
#pragma unroll
      for (int j = 0; j < 8; ++j)
        bfr[fn][j] = (short)f2bf(en_emb[(size_t)idx8[j] * EMBD + e]);
    }
#pragma unroll
    for (int fm = 0; fm < 2; ++fm)
#pragma unroll
      for (int fn = 0; fn < 2; ++fn)
        acc[fm][fn] = __builtin_amdgcn_mfma_f32_16x16x32_bf16(afr[fm], bfr[fn], acc[fm][fn], 0, 0, 0);
  }
  float* pz = part + (size_t)kz * (B_ * EMBD);
#pragma unroll
  for (int fm = 0; fm < 2; ++fm)
#pragma unroll
    for (int fn = 0; fn < 2; ++fn) {
      const int n = n0 + fn * 16 + r16;
#pragma unroll
      for (int j = 0; j < 4; ++j) {
        const int m = m0 + fm * 16 + g * 4 + j;
        pz[(size_t)m * EMBD + n] = acc[fm][fn][j];
      }
    }
}

// ---------------- K1b: reduce splits + bias + selu -> z1 (f32) --------------
__global__ void k1_reduce(const float* __restrict__ part,
                          const float* __restrict__ en_bias,
                          float* __restrict__ z1) {
  const int i = blockIdx.x * blockDim.x + threadIdx.x;
  float s = 0.f;
#pragma unroll
  for (int p = 0; p < SPLITS; ++p) s += part[(size_t)p * (B_ * EMBD) + i];
  z1[i] = selu_f(s + en_bias[i & (EMBD - 1)]);
}

// ---------------- K2/K3: small MLP GEMM (C = A @ Bw^T), register-only -------
template <int KDIM, int LDA, int LDB, bool BF16OUT>
__global__ void mlp_gemm(const float* __restrict__ A,
                         const float* __restrict__ Bw,
                         const float* __restrict__ bias,
                         float* __restrict__ outF,
                         unsigned short* __restrict__ outB,
                         int ldo) {
  const int tid = threadIdx.x;
  const int lane = tid & 63, wave = tid >> 6;
  const int wm = wave >> 1, wn = wave & 1;
  const int g = lane >> 4, r16 = lane & 15;
  const int m0 = blockIdx.x * 64 + wm * 32;
  const int n0 = blockIdx.y * 64 + wn * 32;

  const f32x4 z4 = {0.f, 0.f, 0.f, 0.f};
  f32x4 acc[2][2];
#pragma unroll
  for (int a = 0; a < 2; ++a)
#pragma unroll
    for (int b = 0; b < 2; ++b) acc[a][b] = z4;

#pragma unroll
  for (int k = 0; k < KDIM; k += 32) {
    const int kb = k + g * 8;
    bf16x8 afr[2], bfr[2];
#pragma unroll
    for (int fm = 0; fm < 2; ++fm)
      afr[fm] = load8f(A + (size_t)(m0 + fm * 16 + r16) * LDA + kb);
#pragma unroll
    for (int fn = 0; fn < 2; ++fn)
      bfr[fn] = load8f(Bw + (size_t)(n0 + fn * 16 + r16) * LDB + kb);
#pragma unroll
    for (int fm = 0; fm < 2; ++fm)
#pragma unroll
      for (int fn = 0; fn < 2; ++fn)
        acc[fm][fn] = __builtin_amdgcn_mfma_f32_16x16x32_bf16(afr[fm], bfr[fn], acc[fm][fn], 0, 0, 0);
  }
#pragma unroll
  for (int fm = 0; fm < 2; ++fm)
#pragma unroll
    for (int fn = 0; fn < 2; ++fn) {
      const int n = n0 + fn * 16 + r16;
      const float bv = bias[n];
#pragma unroll
      for (int j = 0; j < 4; ++j) {
        const int m = m0 + fm * 16 + g * 4 + j;
        const float v = selu_f(acc[fm][fn][j] + bv);
        if constexpr (BF16OUT)
          outB[(size_t)m * ldo + n] = f2bf(v);
        else
          outF[(size_t)m * ldo + n] = v;
      }
    }
}

// ---------------- K4: out = z3b @ de_emb^T + de_bias ------------------------
// R10 configuration VERBATIM (best measured: 265.7us total): 128-col
// n-panel (512B/row), Bs nt-staged + XOR-swizzled, double-buffered Cs
// 16-row substeps, lgkm-only barriers, NT full-line stores.
__global__ void k4_decode(const unsigned short* __restrict__ z3b,  // [512][256] bf16
                          const float* __restrict__ de_emb,        // [NEMB][256]
                          const float* __restrict__ de_bias,       // [NEMB]
                          float* __restrict__ out) {               // [512][NEMB]
  __shared__ unsigned short Bs[TILE_N * 256];         // 64 KB, swizzled bf16
  __shared__ __align__(16) float Cs[2][16 * 128];     // 16 KB dbuf, XOR-swz

  const int n0 = blockIdx.x * TILE_N;
  const int tid = threadIdx.x;

  // ---- stage de_emb tile -> Bs (bf16, swizzled); NT loads (single-use) ----
  {
    const int sr = tid >> 2, sq = tid & 3;  // row 0..127, k-quarter 0..3
    const int nrow = n0 + sr;
    const float* src = de_emb + (size_t)nrow * EMBD;
#pragma unroll
    for (int i = 0; i < 8; ++i) {
      const int k0 = i * 32 + sq * 8;
      u16x8 v;
      if (nrow < NEMB) {
        f32x4 x = __builtin_nontemporal_load((const f32x4*)(src + k0));
        f32x4 y = __builtin_nontemporal_load((const f32x4*)(src + k0 + 4));
        v[0] = f2bf(x[0]); v[1] = f2bf(x[1]); v[2] = f2bf(x[2]); v[3] = f2bf(x[3]);
        v[4] = f2bf(y[0]); v[5] = f2bf(y[1]); v[6] = f2bf(y[2]); v[7] = f2bf(y[3]);
      } else {
#pragma unroll
        for (int t = 0; t < 8; ++t) v[t] = 0;
      }
      const int sidx = sr * 256 + (k0 ^ ((sr & 7) << 3));
      *(u16x8*)(&Bs[sidx]) = v;
    }
  }
  __syncthreads();  // one-time

  const int lane = tid & 63, wave = tid >> 6;  // 8 waves
  const int wM = wave >> 1, wN = wave & 1;     // 4(M) x 2(N)
  const int g = lane >> 4, r16 = lane & 15;

  f32x4 biasv[4];
#pragma unroll
  for (int fn = 0; fn < 4; ++fn) {
    const int n = n0 + wN * 64 + fn * 16 + g * 4;
    if (n < NEMB) biasv[fn] = *(const f32x4*)(de_bias + n);
    else { biasv[fn][0] = biasv[fn][1] = biasv[fn][2] = biasv[fn][3] = 0.f; }
  }

  // store-side lane mapping (full-line 512B row segments)
  const int srow = tid >> 5;         // 0..15
  const int scol = (tid & 31) * 4;   // 0..124

  const f32x4 z4 = {0.f, 0.f, 0.f, 0.f};
  for (int mc = 0; mc < 4; ++mc) {
    f32x4 acc[4][2];  // [fn][fm]
#pragma unroll
    for (int a = 0; a < 4; ++a)
#pragma unroll
      for (int b = 0; b < 2; ++b) acc[a][b] = z4;

#pragma unroll
    for (int kk = 0; kk < 8; ++kk) {
      bf16x8 a[2];
#pragma unroll
      for (int fm = 0; fm < 2; ++fm) {
        const int m = mc * 128 + wM * 32 + fm * 16 + r16;
        a[fm] = *(const bf16x8*)(z3b + (size_t)m * EMBD + kk * 32 + g * 8);
      }
#pragma unroll
      for (int fn = 0; fn < 4; ++fn) {
        const int rr = wN * 64 + fn * 16 + r16;
        const int koff = (kk * 32 + g * 8) ^ ((rr & 7) << 3);
        const bf16x8 b = *(const bf16x8*)(&Bs[rr * 256 + koff]);
#pragma unroll
        for (int fm = 0; fm < 2; ++fm)
          acc[fn][fm] = __builtin_amdgcn_mfma_f32_16x16x32_bf16(b, a[fm], acc[fn][fm], 0, 0, 0);
      }
    }

    // ---- double-buffered epilogue: raw barriers, NT full-line stores ----
    if (wM == 0) {
#pragma unroll
      for (int fn = 0; fn < 4; ++fn) {
        const int nl = wN * 64 + fn * 16 + g * 4;
        *(f32x4*)(&Cs[0][r16 * 128 + (nl ^ ((r16 & 7) << 2))]) = acc[fn][0] + biasv[fn];
      }
    }
    barrier_lgkm();
#pragma unroll
    for (int h = 0; h < 8; ++h) {
      if (h < 7 && wM == ((h + 1) >> 1)) {
        const int fm = (h + 1) & 1;
#pragma unroll
        for (int fn = 0; fn < 4; ++fn) {
          const int nl = wN * 64 + fn * 16 + g * 4;
          *(f32x4*)(&Cs[(h + 1) & 1][r16 * 128 + (nl ^ ((r16 & 7) << 2))]) =
              acc[fn][fm] + biasv[fn];
        }
      }
      // stream 16 rows x 512B (full lines) from buf h&1 — NON-TEMPORAL
      const int n = n0 + scol;
      if (n < NEMB) {
        const int m = mc * 128 + h * 16 + srow;
        const f32x4 v = *(const f32x4*)(&Cs[h & 1][srow * 128 + (scol ^ ((srow & 7) << 2))]);
        __builtin_nontemporal_store(v, (f32x4*)(out + (size_t)m * NEMB + n));
      }
      barrier_lgkm();
    }
  }
}

extern "C" void kernel_launch(void* const* d_in, const int* in_sizes, int n_in,
                              void* d_out, int out_size, void* d_ws, size_t ws_size,
                              hipStream_t stream) {
  (void)in_sizes; (void)n_in; (void)out_size;
  const float* rin     = (const float*)d_in[0];
  const int*   act     = (const int*)d_in[1];
  const float* en_emb  = (const float*)d_in[2];
  const float* en_bias = (const float*)d_in[3];
  const float* enc_W   = (const float*)d_in[4];
  const float* enc_b   = (const float*)d_in[5];
  const float* dec_W   = (const float*)d_in[6];
  const float* dec_b   = (const float*)d_in[7];
  const float* de_emb  = (const float*)d_in[8];
  const float* de_bias = (const float*)d_in[9];
  float* out = (float*)d_out;

  // ws layout (bytes): part | z1 | z2 | z3b | wactP
  float* ws   = (float*)d_ws;
  float* part = ws;
  float* z1   = part + (size_t)SPLITS * (B_ * EMBD);
  float* z2   = z1 + (size_t)B_ * EMBD;
  unsigned short* z3b = (unsigned short*)(z2 + (size_t)B_ * HIDD);
  unsigned short* wactP = z3b + (size_t)B_ * EMBD;
  const size_t need = ((size_t)SPLITS * B_ * EMBD + B_ * EMBD + B_ * HIDD) * 4
                      + (size_t)B_ * EMBD * 2 + (size_t)KD * EMBD * 2;

  if (ws_size >= need) {
    k0_pack<<<dim3(KD / 8), 256, 0, stream>>>(act, en_emb, wactP);
    k1_dense<<<dim3(4, 2, SPLITS), 512, 0, stream>>>(rin, wactP, part);
  } else {
    k1_gather_gemm<<<dim3(8, 4, SPLITS), 256, 0, stream>>>(rin, act, en_emb, part);
  }
  k1_reduce<<<dim3((B_ * EMBD) / 256), 256, 0, stream>>>(part, en_bias, z1);
  mlp_gemm<EMBD, EMBD, EMBD, false><<<dim3(8, 8), 256, 0, stream>>>(z1, enc_W, enc_b, z2, nullptr, HIDD);
  mlp_gemm<HIDD, HIDD, HIDD, true><<<dim3(8, 4), 256, 0, stream>>>(z2, dec_W, dec_b, nullptr, z3b, EMBD);
  k4_decode<<<dim3((NEMB + TILE_N - 1) / TILE_N), 512, 0, stream>>>(z3b, de_emb, de_bias, out);
}